// Round 1
// 1976.107 us; speedup vs baseline: 2.5797x; 2.5797x over previous
//
#include <hip/hip_runtime.h>
#include <hip/hip_cooperative_groups.h>
#include <stdint.h>

namespace cg = cooperative_groups;

#define T_STEPS 64
#define B_SZ    64
#define H_SZ    512
#define E_SZ    256
#define V_SZ    32000
#define G4      2048   // 4*H

typedef _Float16 f16;
typedef _Float16 f16x4 __attribute__((ext_vector_type(4)));
typedef _Float16 f16x8 __attribute__((ext_vector_type(8)));
typedef float    f32x4 __attribute__((ext_vector_type(4)));

// ---- addrspace helpers for global_load_lds (generic->AS via integer, compile-safe) ----
#define GLL(g, l) __builtin_amdgcn_global_load_lds(                                   \
    (const __attribute__((address_space(1))) void*)(uintptr_t)(g),                    \
    (__attribute__((address_space(3))) void*)(uint32_t)(uintptr_t)(l), 16, 0, 0)

__device__ __forceinline__ float sigmoidf_fast(float x) {
    return 1.0f / (1.0f + __expf(-x));          // safe for all x (exp>=0)
}
__device__ __forceinline__ float tanhf_fast(float x) {
    return 2.0f / (1.0f + __expf(-2.0f * x)) - 1.0f;  // safe for all x
}

__device__ __forceinline__ f16x4 cvt4(float4 s) {
    f16x4 d; d[0] = (f16)s.x; d[1] = (f16)s.y; d[2] = (f16)s.z; d[3] = (f16)s.w; return d;
}

// ---------------------------------------------------------------------------
// Prep: convert W_out to f16; reorder W_ih rows and bias to n=j*4+g order;
// reorder W_hh -> Wr[j*4+g][k] f16; gather+convert embeddings; h0 -> f16 hbuf0.
// ---------------------------------------------------------------------------
__global__ __launch_bounds__(256) void prep_kernel(
    const float* __restrict__ Wih, const float* __restrict__ Whh,
    const float* __restrict__ Wout, const float* __restrict__ bih,
    const float* __restrict__ bhh, const float* __restrict__ embed,
    const int* __restrict__ y, const float* __restrict__ h0,
    f16* __restrict__ Xf, f16* __restrict__ Wihf, f16* __restrict__ Wrf,
    f16* __restrict__ Woutf, float* __restrict__ bsum, f16* __restrict__ hbuf)
{
    const int NW_OUT = V_SZ * H_SZ / 4;          // 4,096,000
    const int NW_IH  = G4 * E_SZ / 4;            // 131,072
    const int NW_HH  = G4 * H_SZ / 4;            // 262,144
    const int NW_X   = T_STEPS * B_SZ * E_SZ / 4;// 262,144
    const int NW_B   = G4 / 4;                   // 512
    const int NW_H0  = B_SZ * H_SZ / 4;          // 8,192
    const int total  = NW_OUT + NW_IH + NW_HH + NW_X + NW_B + NW_H0;

    for (int u = blockIdx.x * blockDim.x + threadIdx.x; u < total;
         u += gridDim.x * blockDim.x) {
        int v = u;
        if (v < NW_OUT) {                          // W_out straight convert
            ((f16x4*)Woutf)[v] = cvt4(((const float4*)Wout)[v]);
            continue;
        }
        v -= NW_OUT;
        if (v < NW_IH) {                           // W_ih row reorder: dest row j*4+g <- src row g*512+j
            int row = v >> 6;                      // /(256/4)
            int e4  = v & 63;
            int j = row >> 2, g = row & 3;
            ((f16x4*)Wihf)[v] = cvt4(((const float4*)Wih)[(g * H_SZ + j) * (E_SZ / 4) + e4]);
            continue;
        }
        v -= NW_IH;
        if (v < NW_HH) {                           // W_hh reorder: Wr[(j*4+g)*512+k]=Whh[g*512+j][k]
            int row = v >> 7;                      // /(512/4)
            int k4  = v & 127;
            int j = row >> 2, g = row & 3;
            ((f16x4*)Wrf)[v] = cvt4(((const float4*)Whh)[(g * H_SZ + j) * (H_SZ / 4) + k4]);
            continue;
        }
        v -= NW_HH;
        if (v < NW_X) {                            // embed gather
            int tb = v >> 6;                       // /(256/4)
            int e4 = v & 63;
            int t = tb >> 6, b = tb & 63;
            int tok = (t == 0) ? 1 : y[(t - 1) * B_SZ + b];
            ((f16x4*)Xf)[v] = cvt4(((const float4*)embed)[tok * (E_SZ / 4) + e4]);
            continue;
        }
        v -= NW_X;
        if (v < NW_B) {                            // bias sum, reordered: bsum[4v+g] = bih[g*512+v]+bhh[g*512+v]
            float4 s;
            s.x = bih[0 * H_SZ + v] + bhh[0 * H_SZ + v];
            s.y = bih[1 * H_SZ + v] + bhh[1 * H_SZ + v];
            s.z = bih[2 * H_SZ + v] + bhh[2 * H_SZ + v];
            s.w = bih[3 * H_SZ + v] + bhh[3 * H_SZ + v];
            ((float4*)bsum)[v] = s;
            continue;
        }
        v -= NW_B;                                 // h0 -> f16 into hbuf[0]
        ((f16x4*)hbuf)[v] = cvt4(((const float4*)h0)[v]);
    }
}

// ---------------------------------------------------------------------------
// MFMA f16 GEMM: C[M,N] = A[M,K] @ B[N,K]^T + bias[N]   (f32 out)
// 128x128 tile, 4 waves (2x2), each wave 64x64 = 4x4 of 16x16x32 MFMA.
// global_load_lds width-16 staging. M%128==0, N%128==0, K%32==0 required.
// ---------------------------------------------------------------------------
template <int K>
__global__ __launch_bounds__(256) void gemm_f16(
    const f16* __restrict__ A, const f16* __restrict__ Bm,
    const float* __restrict__ bias, float* __restrict__ C, int N)
{
    __shared__ f16 As[128 * 32];
    __shared__ f16 Bs[128 * 32];
    const int tid  = threadIdx.x;
    const int wave = tid >> 6;
    const int lane = tid & 63;
    const int m0 = blockIdx.y * 128;
    const int n0 = blockIdx.x * 128;
    const int wm = (wave >> 1) * 64;
    const int wn = (wave & 1) * 64;

    f32x4 acc[4][4] = {};

    const int srow = wave * 32 + (lane >> 2);
    const int skk  = (lane & 3) * 8;
    const f16* gA0 = A + (size_t)(m0 + srow) * K + skk;
    const f16* gA1 = gA0 + 16 * K;
    const f16* gB0 = Bm + (size_t)(n0 + srow) * K + skk;
    const f16* gB1 = gB0 + 16 * K;
    f16* lA0 = As + wave * 1024;   // 32 rows * 32 f16
    f16* lA1 = lA0 + 512;
    f16* lB0 = Bs + wave * 1024;
    f16* lB1 = lB0 + 512;

    const int fr = lane & 15;
    const int fk = (lane >> 4) * 8;
    const f16* rA = As + fr * 32 + fk;
    const f16* rB = Bs + fr * 32 + fk;

    for (int k0 = 0; k0 < K; k0 += 32) {
        GLL(gA0, lA0); GLL(gA1, lA1); GLL(gB0, lB0); GLL(gB1, lB1);
        gA0 += 32; gA1 += 32; gB0 += 32; gB1 += 32;
        __syncthreads();   // drains vmcnt (global_load_lds) + barrier

        f16x8 af[4], bf[4];
#pragma unroll
        for (int mt = 0; mt < 4; ++mt) af[mt] = *(const f16x8*)(rA + (wm + mt * 16) * 32);
#pragma unroll
        for (int nt = 0; nt < 4; ++nt) bf[nt] = *(const f16x8*)(rB + (wn + nt * 16) * 32);
#pragma unroll
        for (int mt = 0; mt < 4; ++mt)
#pragma unroll
            for (int nt = 0; nt < 4; ++nt)
                acc[mt][nt] = __builtin_amdgcn_mfma_f32_16x16x32_f16(af[mt], bf[nt],
                                                                     acc[mt][nt], 0, 0, 0);
        __syncthreads();
    }

    const int crow = (lane >> 4) * 4;
    const int ccol = lane & 15;
#pragma unroll
    for (int nt = 0; nt < 4; ++nt) {
        const int n  = n0 + wn + nt * 16 + ccol;
        const float bn = bias[n];
#pragma unroll
        for (int mt = 0; mt < 4; ++mt) {
            const int m = m0 + wm + mt * 16 + crow;
            size_t base = (size_t)m * N + n;
#pragma unroll
            for (int r = 0; r < 4; ++r)
                C[base + (size_t)r * N] = acc[mt][nt][r] + bn;
        }
    }
}

// ---------------------------------------------------------------------------
// Cooperative LSTM recurrence: 64 blocks x 256 threads, grid.sync() per step.
// Block b owns 32 rows of Wr (n = j*4+g, j in [8b, 8b+8)) held in REGISTERS
// as MFMA B-fragments (loaded once). Per step: stage h[64,512] f16 -> LDS,
// one 64x32x512 MFMA pass (wave w = samples 16w..16w+16), add Gx (already in
// j*4+g column order), gate math with persistent c in registers, write h
// (f16, double-buffered global) + Cb cell state, grid sync.
// ---------------------------------------------------------------------------
#define HS_PAD 520   // 512 + 8 f16: rotates banks by 4/row -> 2-way (free)

__global__ __launch_bounds__(256) void lstm_coop(
    const float* __restrict__ c0, const float* __restrict__ Gx,
    const f16* __restrict__ Wr, f16* __restrict__ hbuf,
    f16* __restrict__ Cb)
{
    cg::grid_group grid = cg::this_grid();
    const int tid  = threadIdx.x;
    const int wave = tid >> 6;
    const int lane = tid & 63;
    const int blk  = blockIdx.x;
    const int n0   = blk * 32;

    __shared__ f16   hs[64 * HS_PAD];   // 66,560 B
    __shared__ float gacc[64 * 32];     //  8,192 B

    // --- preload B fragments: Wr rows [n0, n0+32), K=512 -> 128 VGPRs ---
    f16x8 bf[2][16];
    {
        const int fr  = lane & 15;
        const int fko = (lane >> 4) * 8;
#pragma unroll
        for (int nt = 0; nt < 2; ++nt)
#pragma unroll
            for (int ks = 0; ks < 16; ++ks)
                bf[nt][ks] = *(const f16x8*)(Wr + (size_t)(n0 + nt * 16 + fr) * H_SZ
                                             + ks * 32 + fko);
    }

    // --- persistent cell state: thread owns (m0p, jl) and (m0p+32, jl) ---
    const int m0p = tid >> 3;          // 0..31
    const int jl  = tid & 7;
    const int jg  = blk * 8 + jl;
    float cst0 = c0[m0p * H_SZ + jg];
    float cst1 = c0[(m0p + 32) * H_SZ + jg];

    for (int t = 0; t < T_STEPS; ++t) {
        const f16* hsrc = hbuf + (size_t)(t & 1) * (B_SZ * H_SZ);
        f16*       hdst = hbuf + (size_t)((t + 1) & 1) * (B_SZ * H_SZ);

        // stage h -> LDS (padded rows); 16 x 16B chunks per thread, 2 batches
#pragma unroll
        for (int half = 0; half < 2; ++half) {
            f16x8 v[8];
#pragma unroll
            for (int i = 0; i < 8; ++i) {
                int id = tid + 256 * (half * 8 + i);
                v[i] = *(const f16x8*)(hsrc + id * 8);
            }
#pragma unroll
            for (int i = 0; i < 8; ++i) {
                int id  = tid + 256 * (half * 8 + i);
                int row = id >> 6, c8 = id & 63;
                *(f16x8*)(hs + row * HS_PAD + c8 * 8) = v[i];
            }
        }
        __syncthreads();

        // MFMA: samples [16*wave, 16*wave+16) x 32 n-cols, K=512
        f32x4 acc0 = {}, acc1 = {};
        {
            const f16* ra = hs + (16 * wave + (lane & 15)) * HS_PAD + (lane >> 4) * 8;
#pragma unroll
            for (int ks = 0; ks < 16; ++ks) {
                f16x8 af = *(const f16x8*)(ra + ks * 32);
                acc0 = __builtin_amdgcn_mfma_f32_16x16x32_f16(af, bf[0][ks], acc0, 0, 0, 0);
                acc1 = __builtin_amdgcn_mfma_f32_16x16x32_f16(af, bf[1][ks], acc1, 0, 0, 0);
            }
        }
        // C/D layout: col=lane&15, row=(lane>>4)*4+reg -> gacc[m][ln]
        {
            const int ccol = lane & 15;
            const int crow = 16 * wave + (lane >> 4) * 4;
#pragma unroll
            for (int r = 0; r < 4; ++r) {
                gacc[(crow + r) * 32 + ccol]      = acc0[r];
                gacc[(crow + r) * 32 + 16 + ccol] = acc1[r];
            }
        }
        __syncthreads();

        // gates + state update: 2 (m, jl) pairs per thread
        const float* gxt = Gx + (size_t)(t * B_SZ) * G4;
        {
            const int m = m0p;
            float4 gx = *(const float4*)(gxt + (size_t)m * G4 + n0 + jl * 4);
            float4 ac = *(const float4*)(gacc + m * 32 + jl * 4);
            float ig = sigmoidf_fast(ac.x + gx.x);
            float fg = sigmoidf_fast(ac.y + gx.y);
            float gg = tanhf_fast(ac.z + gx.z);
            float og = sigmoidf_fast(ac.w + gx.w);
            cst0 = fg * cst0 + ig * gg;
            float hn = og * tanhf_fast(cst0);
            Cb[(size_t)(t * B_SZ + m) * H_SZ + jg] = (f16)cst0;
            hdst[m * H_SZ + jg] = (f16)hn;
        }
        {
            const int m = m0p + 32;
            float4 gx = *(const float4*)(gxt + (size_t)m * G4 + n0 + jl * 4);
            float4 ac = *(const float4*)(gacc + m * 32 + jl * 4);
            float ig = sigmoidf_fast(ac.x + gx.x);
            float fg = sigmoidf_fast(ac.y + gx.y);
            float gg = tanhf_fast(ac.z + gx.z);
            float og = sigmoidf_fast(ac.w + gx.w);
            cst1 = fg * cst1 + ig * gg;
            float hn = og * tanhf_fast(cst1);
            Cb[(size_t)(t * B_SZ + m) * H_SZ + jg] = (f16)cst1;
            hdst[m * H_SZ + jg] = (f16)hn;
        }

        __threadfence();   // make h stores visible device-wide before the barrier
        grid.sync();
    }
}

// ---------------------------------------------------------------------------
extern "C" void kernel_launch(void* const* d_in, const int* in_sizes, int n_in,
                              void* d_out, int out_size, void* d_ws, size_t ws_size,
                              hipStream_t stream)
{
    const float* h0    = (const float*)d_in[0];
    const float* c0    = (const float*)d_in[1];
    // d_in[2] = context: unused by the reference
    const int*   y     = (const int*)d_in[3];
    const float* embed = (const float*)d_in[4];
    const float* Wih   = (const float*)d_in[5];
    const float* bih   = (const float*)d_in[6];
    const float* Whh   = (const float*)d_in[7];
    const float* bhh   = (const float*)d_in[8];
    const float* Wout  = (const float*)d_in[9];
    const float* bout  = (const float*)d_in[10];
    float* out = (float*)d_out;

    char* ws = (char*)d_ws;
    f16*   Woutf = (f16*)ws;   ws += (size_t)V_SZ * H_SZ * 2;        // 32,768,000
    float* Gx    = (float*)ws; ws += (size_t)T_STEPS * B_SZ * G4 * 4;// 33,554,432
    f16*   Xf    = (f16*)ws;   ws += (size_t)T_STEPS * B_SZ * E_SZ * 2; // 2,097,152
    f16*   Wihf  = (f16*)ws;   ws += (size_t)G4 * E_SZ * 2;          // 1,048,576
    f16*   Wrf   = (f16*)ws;   ws += (size_t)G4 * H_SZ * 2;          // 2,097,152
    f16*   Cb    = (f16*)ws;   ws += (size_t)T_STEPS * B_SZ * H_SZ * 2; // 4,194,304
    float* bsum  = (float*)ws; ws += (size_t)G4 * 4;                 // 8,192
    f16*   hbuf  = (f16*)ws;   ws += (size_t)2 * B_SZ * H_SZ * 2;    // 131,072 (double buffer)

    prep_kernel<<<4096, 256, 0, stream>>>(Wih, Whh, Wout, bih, bhh, embed, y, h0,
                                          Xf, Wihf, Wrf, Woutf, bsum, hbuf);
    // Gx[tb][n] = X @ W_ih^T + (b_ih + b_hh), columns already in n=j*4+g order
    gemm_f16<E_SZ><<<dim3(G4 / 128, (T_STEPS * B_SZ) / 128), 256, 0, stream>>>(
        Xf, Wihf, bsum, Gx, G4);

    // cooperative LSTM recurrence (grid.sync per step)
    {
        const float* c0_  = c0;
        const float* Gx_  = Gx;
        const f16*   Wr_  = Wrf;
        f16*         hb_  = hbuf;
        f16*         Cb_  = Cb;
        void* kargs[] = {(void*)&c0_, (void*)&Gx_, (void*)&Wr_, (void*)&hb_, (void*)&Cb_};
        hipLaunchCooperativeKernel((const void*)lstm_coop, dim3(B_SZ), dim3(256),
                                   kargs, 0, stream);
    }

    // out[tb][v] = C_cell @ W_out^T + b_out
    gemm_f16<H_SZ><<<dim3(V_SZ / 128, (T_STEPS * B_SZ) / 128), 256, 0, stream>>>(
        Cb, Woutf, bout, out, V_SZ);
}

// Round 4
// 1205.109 us; speedup vs baseline: 4.2301x; 1.6398x over previous
//
#include <hip/hip_runtime.h>
#include <stdint.h>

#define T_STEPS 64
#define B_SZ    64
#define H_SZ    512
#define E_SZ    256
#define V_SZ    32000
#define G4      2048   // 4*H
#define NBLK    64     // lstm blocks (verified geometry: 32 gate-rows each)

typedef _Float16 f16;
typedef _Float16 f16x4 __attribute__((ext_vector_type(4)));
typedef _Float16 f16x8 __attribute__((ext_vector_type(8)));
typedef float    f32x4 __attribute__((ext_vector_type(4)));

// ---- addrspace helpers for global_load_lds (generic->AS via integer, compile-safe) ----
#define GLL(g, l) __builtin_amdgcn_global_load_lds(                                   \
    (const __attribute__((address_space(1))) void*)(uintptr_t)(g),                    \
    (__attribute__((address_space(3))) void*)(uint32_t)(uintptr_t)(l), 16, 0, 0)

__device__ __forceinline__ float sigmoidf_fast(float x) {
    return 1.0f / (1.0f + __expf(-x));          // safe for all x (exp>=0)
}
__device__ __forceinline__ float tanhf_fast(float x) {
    return 2.0f / (1.0f + __expf(-2.0f * x)) - 1.0f;  // safe for all x
}

__device__ __forceinline__ f16x4 cvt4(float4 s) {
    f16x4 d; d[0] = (f16)s.x; d[1] = (f16)s.y; d[2] = (f16)s.z; d[3] = (f16)s.w; return d;
}

// ---------------------------------------------------------------------------
// Prep: convert W_out to f16; reorder W_ih rows and bias to n=j*4+g order;
// reorder W_hh -> Wr[j*4+g][k] f16; gather+convert embeddings; h0 -> f16 hbuf0;
// zero the lstm barrier counter.
// ---------------------------------------------------------------------------
__global__ __launch_bounds__(256) void prep_kernel(
    const float* __restrict__ Wih, const float* __restrict__ Whh,
    const float* __restrict__ Wout, const float* __restrict__ bih,
    const float* __restrict__ bhh, const float* __restrict__ embed,
    const int* __restrict__ y, const float* __restrict__ h0,
    f16* __restrict__ Xf, f16* __restrict__ Wihf, f16* __restrict__ Wrf,
    f16* __restrict__ Woutf, float* __restrict__ bsum, f16* __restrict__ hbuf,
    unsigned int* __restrict__ bar)
{
    if (blockIdx.x == 0 && threadIdx.x == 0) *bar = 0u;

    const int NW_OUT = V_SZ * H_SZ / 4;          // 4,096,000
    const int NW_IH  = G4 * E_SZ / 4;            // 131,072
    const int NW_HH  = G4 * H_SZ / 4;            // 262,144
    const int NW_X   = T_STEPS * B_SZ * E_SZ / 4;// 262,144
    const int NW_B   = G4 / 4;                   // 512
    const int NW_H0  = B_SZ * H_SZ / 4;          // 8,192
    const int total  = NW_OUT + NW_IH + NW_HH + NW_X + NW_B + NW_H0;

    for (int u = blockIdx.x * blockDim.x + threadIdx.x; u < total;
         u += gridDim.x * blockDim.x) {
        int v = u;
        if (v < NW_OUT) {                          // W_out straight convert
            ((f16x4*)Woutf)[v] = cvt4(((const float4*)Wout)[v]);
            continue;
        }
        v -= NW_OUT;
        if (v < NW_IH) {                           // W_ih row reorder: dest row j*4+g <- src row g*512+j
            int row = v >> 6;                      // /(256/4)
            int e4  = v & 63;
            int j = row >> 2, g = row & 3;
            ((f16x4*)Wihf)[v] = cvt4(((const float4*)Wih)[(g * H_SZ + j) * (E_SZ / 4) + e4]);
            continue;
        }
        v -= NW_IH;
        if (v < NW_HH) {                           // W_hh reorder: Wr[(j*4+g)*512+k]=Whh[g*512+j][k]
            int row = v >> 7;                      // /(512/4)
            int k4  = v & 127;
            int j = row >> 2, g = row & 3;
            ((f16x4*)Wrf)[v] = cvt4(((const float4*)Whh)[(g * H_SZ + j) * (H_SZ / 4) + k4]);
            continue;
        }
        v -= NW_HH;
        if (v < NW_X) {                            // embed gather
            int tb = v >> 6;                       // /(256/4)
            int e4 = v & 63;
            int t = tb >> 6, b = tb & 63;
            int tok = (t == 0) ? 1 : y[(t - 1) * B_SZ + b];
            ((f16x4*)Xf)[v] = cvt4(((const float4*)embed)[tok * (E_SZ / 4) + e4]);
            continue;
        }
        v -= NW_X;
        if (v < NW_B) {                            // bias sum, reordered: bsum[4v+g] = bih[g*512+v]+bhh[g*512+v]
            float4 s;
            s.x = bih[0 * H_SZ + v] + bhh[0 * H_SZ + v];
            s.y = bih[1 * H_SZ + v] + bhh[1 * H_SZ + v];
            s.z = bih[2 * H_SZ + v] + bhh[2 * H_SZ + v];
            s.w = bih[3 * H_SZ + v] + bhh[3 * H_SZ + v];
            ((float4*)bsum)[v] = s;
            continue;
        }
        v -= NW_B;                                 // h0 -> f16 into hbuf[0]
        ((f16x4*)hbuf)[v] = cvt4(((const float4*)h0)[v]);
    }
}

// ---------------------------------------------------------------------------
// MFMA f16 GEMM: C[M,N] = A[M,K] @ B[N,K]^T + bias[N]   (f32 out)
// 128x128 tile, 4 waves (2x2), each wave 64x64 = 4x4 of 16x16x32 MFMA.
// ---------------------------------------------------------------------------
template <int K>
__global__ __launch_bounds__(256) void gemm_f16(
    const f16* __restrict__ A, const f16* __restrict__ Bm,
    const float* __restrict__ bias, float* __restrict__ C, int N)
{
    __shared__ f16 As[128 * 32];
    __shared__ f16 Bs[128 * 32];
    const int tid  = threadIdx.x;
    const int wave = tid >> 6;
    const int lane = tid & 63;
    const int m0 = blockIdx.y * 128;
    const int n0 = blockIdx.x * 128;
    const int wm = (wave >> 1) * 64;
    const int wn = (wave & 1) * 64;

    f32x4 acc[4][4] = {};

    const int srow = wave * 32 + (lane >> 2);
    const int skk  = (lane & 3) * 8;
    const f16* gA0 = A + (size_t)(m0 + srow) * K + skk;
    const f16* gA1 = gA0 + 16 * K;
    const f16* gB0 = Bm + (size_t)(n0 + srow) * K + skk;
    const f16* gB1 = gB0 + 16 * K;
    f16* lA0 = As + wave * 1024;   // 32 rows * 32 f16
    f16* lA1 = lA0 + 512;
    f16* lB0 = Bs + wave * 1024;
    f16* lB1 = lB0 + 512;

    const int fr = lane & 15;
    const int fk = (lane >> 4) * 8;
    const f16* rA = As + fr * 32 + fk;
    const f16* rB = Bs + fr * 32 + fk;

    for (int k0 = 0; k0 < K; k0 += 32) {
        GLL(gA0, lA0); GLL(gA1, lA1); GLL(gB0, lB0); GLL(gB1, lB1);
        gA0 += 32; gA1 += 32; gB0 += 32; gB1 += 32;
        __syncthreads();   // drains vmcnt (global_load_lds) + barrier

        f16x8 af[4], bf[4];
#pragma unroll
        for (int mt = 0; mt < 4; ++mt) af[mt] = *(const f16x8*)(rA + (wm + mt * 16) * 32);
#pragma unroll
        for (int nt = 0; nt < 4; ++nt) bf[nt] = *(const f16x8*)(rB + (wn + nt * 16) * 32);
#pragma unroll
        for (int mt = 0; mt < 4; ++mt)
#pragma unroll
            for (int nt = 0; nt < 4; ++nt)
                acc[mt][nt] = __builtin_amdgcn_mfma_f32_16x16x32_f16(af[mt], bf[nt],
                                                                     acc[mt][nt], 0, 0, 0);
        __syncthreads();
    }

    const int crow = (lane >> 4) * 4;
    const int ccol = lane & 15;
#pragma unroll
    for (int nt = 0; nt < 4; ++nt) {
        const int n  = n0 + wn + nt * 16 + ccol;
        const float bn = bias[n];
#pragma unroll
        for (int mt = 0; mt < 4; ++mt) {
            const int m = m0 + wm + mt * 16 + crow;
            size_t base = (size_t)m * N + n;
#pragma unroll
            for (int r = 0; r < 4; ++r)
                C[base + (size_t)r * N] = acc[mt][nt][r] + bn;
        }
    }
}

// ---------------------------------------------------------------------------
// LSTM recurrence: VERIFIED round-1 compute (64 blocks x 256 threads, block
// owns 32 gate-rows, W in registers, reg+ds_write h staging). Single change:
// the all-thread __threadfence + grid.sync is replaced by a lean barrier —
// __syncthreads (store drain) + tid0-only ACQ_REL arrival + ACQUIRE spin +
// __syncthreads. h/Cb stores are nontemporal (no-allocate L2) so the release
// writeback has almost nothing to walk. Max inter-block skew = 1 step, safe
// under the h double-buffer.
// ---------------------------------------------------------------------------
#define HS_PAD 520   // 512 + 8 f16: rotates banks by 4/row -> 2-way (free)

__global__ __launch_bounds__(256) void lstm_coop(
    const float* __restrict__ c0, const float* __restrict__ Gx,
    const f16* __restrict__ Wr, f16* __restrict__ hbuf,
    f16* __restrict__ Cb, unsigned int* __restrict__ bar)
{
    const int tid  = threadIdx.x;
    const int wave = tid >> 6;
    const int lane = tid & 63;
    const int blk  = blockIdx.x;
    const int n0   = blk * 32;

    __shared__ f16   hs[64 * HS_PAD];   // 66,560 B
    __shared__ float gacc[64 * 32];     //  8,192 B

    // --- preload B fragments: Wr rows [n0, n0+32), K=512 -> 128 regs ---
    f16x8 bf[2][16];
    {
        const int fr  = lane & 15;
        const int fko = (lane >> 4) * 8;
#pragma unroll
        for (int nt = 0; nt < 2; ++nt)
#pragma unroll
            for (int ks = 0; ks < 16; ++ks)
                bf[nt][ks] = *(const f16x8*)(Wr + (size_t)(n0 + nt * 16 + fr) * H_SZ
                                             + ks * 32 + fko);
    }

    // --- persistent cell state: thread owns (m0p, jl) and (m0p+32, jl) ---
    const int m0p = tid >> 3;          // 0..31
    const int jl  = tid & 7;
    const int jg  = blk * 8 + jl;
    float cst0 = c0[m0p * H_SZ + jg];
    float cst1 = c0[(m0p + 32) * H_SZ + jg];

    for (int t = 0; t < T_STEPS; ++t) {
        const f16* hsrc = hbuf + (size_t)(t & 1) * (B_SZ * H_SZ);
        f16*       hdst = hbuf + (size_t)((t + 1) & 1) * (B_SZ * H_SZ);

        // stage h -> LDS (padded rows); 16 x 16B chunks per thread, 2 batches
#pragma unroll
        for (int half = 0; half < 2; ++half) {
            f16x8 v[8];
#pragma unroll
            for (int i = 0; i < 8; ++i) {
                int id = tid + 256 * (half * 8 + i);
                v[i] = *(const f16x8*)(hsrc + id * 8);
            }
#pragma unroll
            for (int i = 0; i < 8; ++i) {
                int id  = tid + 256 * (half * 8 + i);
                int row = id >> 6, c8 = id & 63;
                *(f16x8*)(hs + row * HS_PAD + c8 * 8) = v[i];
            }
        }
        __syncthreads();

        // MFMA: samples [16*wave, 16*wave+16) x 32 n-cols, K=512
        f32x4 acc0 = {}, acc1 = {};
        {
            const f16* ra = hs + (16 * wave + (lane & 15)) * HS_PAD + (lane >> 4) * 8;
#pragma unroll
            for (int ks = 0; ks < 16; ++ks) {
                f16x8 af = *(const f16x8*)(ra + ks * 32);
                acc0 = __builtin_amdgcn_mfma_f32_16x16x32_f16(af, bf[0][ks], acc0, 0, 0, 0);
                acc1 = __builtin_amdgcn_mfma_f32_16x16x32_f16(af, bf[1][ks], acc1, 0, 0, 0);
            }
        }
        // C/D layout: col=lane&15, row=(lane>>4)*4+reg -> gacc[m][ln]
        {
            const int ccol = lane & 15;
            const int crow = 16 * wave + (lane >> 4) * 4;
#pragma unroll
            for (int r = 0; r < 4; ++r) {
                gacc[(crow + r) * 32 + ccol]      = acc0[r];
                gacc[(crow + r) * 32 + 16 + ccol] = acc1[r];
            }
        }
        __syncthreads();

        // gates + state update: 2 (m, jl) pairs per thread
        const float* gxt = Gx + (size_t)(t * B_SZ) * G4;
        {
            const int m = m0p;
            float4 gx = *(const float4*)(gxt + (size_t)m * G4 + n0 + jl * 4);
            float4 ac = *(const float4*)(gacc + m * 32 + jl * 4);
            float ig = sigmoidf_fast(ac.x + gx.x);
            float fg = sigmoidf_fast(ac.y + gx.y);
            float gg = tanhf_fast(ac.z + gx.z);
            float og = sigmoidf_fast(ac.w + gx.w);
            cst0 = fg * cst0 + ig * gg;
            float hn = og * tanhf_fast(cst0);
            __builtin_nontemporal_store((f16)cst0, Cb + (size_t)(t * B_SZ + m) * H_SZ + jg);
            __builtin_nontemporal_store((f16)hn,   hdst + m * H_SZ + jg);
        }
        {
            const int m = m0p + 32;
            float4 gx = *(const float4*)(gxt + (size_t)m * G4 + n0 + jl * 4);
            float4 ac = *(const float4*)(gacc + m * 32 + jl * 4);
            float ig = sigmoidf_fast(ac.x + gx.x);
            float fg = sigmoidf_fast(ac.y + gx.y);
            float gg = tanhf_fast(ac.z + gx.z);
            float og = sigmoidf_fast(ac.w + gx.w);
            cst1 = fg * cst1 + ig * gg;
            float hn = og * tanhf_fast(cst1);
            __builtin_nontemporal_store((f16)cst1, Cb + (size_t)(t * B_SZ + m) * H_SZ + jg);
            __builtin_nontemporal_store((f16)hn,   hdst + m * H_SZ + jg);
        }

        if (t + 1 < T_STEPS) {
            __syncthreads();   // all waves' stores vmcnt-drained (visible at L2/LLC)
            if (tid == 0) {
                // release+acquire at agent scope, once per block (not per thread)
                __hip_atomic_fetch_add(bar, 1u, __ATOMIC_ACQ_REL, __HIP_MEMORY_SCOPE_AGENT);
                const unsigned int tgt = (unsigned int)NBLK * (unsigned int)(t + 1);
                while (__hip_atomic_load(bar, __ATOMIC_ACQUIRE, __HIP_MEMORY_SCOPE_AGENT) < tgt)
                    __builtin_amdgcn_s_sleep(1);
            }
            __syncthreads();
        }
    }
}

// ---------------------------------------------------------------------------
extern "C" void kernel_launch(void* const* d_in, const int* in_sizes, int n_in,
                              void* d_out, int out_size, void* d_ws, size_t ws_size,
                              hipStream_t stream)
{
    const float* h0    = (const float*)d_in[0];
    const float* c0    = (const float*)d_in[1];
    // d_in[2] = context: unused by the reference
    const int*   y     = (const int*)d_in[3];
    const float* embed = (const float*)d_in[4];
    const float* Wih   = (const float*)d_in[5];
    const float* bih   = (const float*)d_in[6];
    const float* Whh   = (const float*)d_in[7];
    const float* bhh   = (const float*)d_in[8];
    const float* Wout  = (const float*)d_in[9];
    const float* bout  = (const float*)d_in[10];
    float* out = (float*)d_out;

    char* ws = (char*)d_ws;
    f16*   Woutf = (f16*)ws;   ws += (size_t)V_SZ * H_SZ * 2;        // 32,768,000
    float* Gx    = (float*)ws; ws += (size_t)T_STEPS * B_SZ * G4 * 4;// 33,554,432
    f16*   Xf    = (f16*)ws;   ws += (size_t)T_STEPS * B_SZ * E_SZ * 2; // 2,097,152
    f16*   Wihf  = (f16*)ws;   ws += (size_t)G4 * E_SZ * 2;          // 1,048,576
    f16*   Wrf   = (f16*)ws;   ws += (size_t)G4 * H_SZ * 2;          // 2,097,152
    f16*   Cb    = (f16*)ws;   ws += (size_t)T_STEPS * B_SZ * H_SZ * 2; // 4,194,304
    float* bsum  = (float*)ws; ws += (size_t)G4 * 4;                 // 8,192
    f16*   hbuf  = (f16*)ws;   ws += (size_t)2 * B_SZ * H_SZ * 2;    // 131,072 (double buffer)
    unsigned int* bar = (unsigned int*)ws; ws += 16;                 // barrier counter

    prep_kernel<<<4096, 256, 0, stream>>>(Wih, Whh, Wout, bih, bhh, embed, y, h0,
                                          Xf, Wihf, Wrf, Woutf, bsum, hbuf, bar);
    // Gx[tb][n] = X @ W_ih^T + (b_ih + b_hh), columns already in n=j*4+g order
    gemm_f16<E_SZ><<<dim3(G4 / 128, (T_STEPS * B_SZ) / 128), 256, 0, stream>>>(
        Xf, Wihf, bsum, Gx, G4);

    // LSTM recurrence (64 blocks, verified compute; cooperative launch for
    // guaranteed co-residency; lean tid0 release/acquire barrier per step)
    {
        const float* c0_  = c0;
        const float* Gx_  = Gx;
        const f16*   Wr_  = Wrf;
        f16*         hb_  = hbuf;
        f16*         Cb_  = Cb;
        unsigned int* bar_ = bar;
        void* kargs[] = {(void*)&c0_, (void*)&Gx_, (void*)&Wr_, (void*)&hb_,
                         (void*)&Cb_, (void*)&bar_};
        hipLaunchCooperativeKernel((const void*)lstm_coop, dim3(NBLK), dim3(256),
                                   kargs, 0, stream);
    }

    // out[tb][v] = C_cell @ W_out^T + b_out
    gemm_f16<H_SZ><<<dim3(V_SZ / 128, (T_STEPS * B_SZ) / 128), 256, 0, stream>>>(
        Cb, Woutf, bout, out, V_SZ);
}